// Round 4
// baseline (408.894 us; speedup 1.0000x reference)
//
#include <hip/hip_runtime.h>

// GameURMAttention: x[65536,512] -> QKV -> 8-head SDPA (S=16,D=64) -> out-proj.
// R7 = R6 + B-operand out of LDS:
//  - weights repacked (repack_wq/repack_wo) into MFMA-fragment order: 1KB chunk
//    per (head,kb,ks,rowgroup) = lane*16B. Wave loads B frags with single
//    coalesced global_load_dwordx4 from L2 (W is L2-resident). No B LDS tile.
//  - B frags for kb+1 prefetched into a 3-slot static register rotation
//    ((2kb)%3 indexing, kb loop fully unrolled -> all indices compile-time).
//  - A unchanged: gld16 DMA, dbuf, XOR source-swizzle (R6-proven).
//  - oproj reverted to m97-proven 256-thr 2x2 wave grid (R5's 512-thr cost
//    ~11us), same B-direct scheme.
//  LDS-read/kb drops 114.7->65.5 KB per CU -> MFMA becomes binding pipe.
// Tiers:
//  tier A (ws>=137MB): xb + attnb + repacked weights
//  tier B (ws>= 70MB): attnb + repacked weights; x converted during staging
//  tier C (ws>=  2MB): wqb repacked, wob OLD-linear (oproj_inplace needs it)
//  tier D:             f32 fragment loads straight from wqkv/wo

#define HID 512

typedef __attribute__((ext_vector_type(4))) float  float4v;
typedef __attribute__((ext_vector_type(8))) short  short8;
typedef __attribute__((ext_vector_type(4))) short  short4v;
typedef __attribute__((ext_vector_type(8))) __bf16 bf16x8;

static __device__ __forceinline__ short bf16rne(float f) {
    union { float f; unsigned u; } v; v.f = f;
    unsigned u = v.u + 0x7FFFu + ((v.u >> 16) & 1u);
    return (short)(u >> 16);
}

static __device__ __forceinline__ short8 pack8(float4v a, float4v b) {
    short8 o;
    o[0] = bf16rne(a[0]); o[1] = bf16rne(a[1]); o[2] = bf16rne(a[2]); o[3] = bf16rne(a[3]);
    o[4] = bf16rne(b[0]); o[5] = bf16rne(b[1]); o[6] = bf16rne(b[2]); o[7] = bf16rne(b[3]);
    return o;
}

static __device__ __forceinline__ void cvt8_store(short* dst, const float* src) {
    float4v a = *(const float4v*)src;
    float4v b = *(const float4v*)(src + 4);
    *(short8*)dst = pack8(a, b);
}

static __device__ __forceinline__ float4v mfma16(short8 a, short8 b, float4v c) {
    union { short8 s; bf16x8 v; } ua, ub;
    ua.s = a; ub.s = b;
    return __builtin_amdgcn_mfma_f32_16x16x32_bf16(ua.v, ub.v, c, 0, 0, 0);
}

// async global->LDS DMA, 16B per lane; l must be wave-uniform (HW adds lane*16).
static __device__ __forceinline__ void gld16(const short* g, short* l) {
    __builtin_amdgcn_global_load_lds(
        (const __attribute__((address_space(1))) void*)g,
        (__attribute__((address_space(3))) void*)l,
        16, 0, 0);
}

// ---------------- cvt: fp32 -> bf16 (linear) ----------------
__global__ void cvt_kernel(const float* __restrict__ src, short* __restrict__ dst, int n4) {
    int i = blockIdx.x * 256 + threadIdx.x;
    if (i >= n4) return;
    float4v v = *(const float4v*)(src + (size_t)i * 4);
    short4v o;
    o[0] = bf16rne(v[0]); o[1] = bf16rne(v[1]); o[2] = bf16rne(v[2]); o[3] = bf16rne(v[3]);
    *(short4v*)(dst + (size_t)i * 4) = o;
}

// ---------------- repack w_qkv -> fragment order ----------------
// chunk i = (((h*8+kb)*2+ks)*12 + g)*64 + lane, data = W[grow(n)][col..col+7]
// n = g*16 + (lane&15); grow = (n>>6)*512 + h*64 + (n&63); col = kb*64+ks*32+(lane>>4)*8.
// total chunks 8*8*2*12*64 = 98304 (= 1.5MB bf16, exactly wqb size).
__global__ void repack_wq_kernel(const float* __restrict__ src, short* __restrict__ dst) {
    int i = blockIdx.x * 256 + threadIdx.x;       // 98304 total
    int lane = i & 63, t = i >> 6;
    int g = t % 12; t /= 12;
    int ks = t & 1; t >>= 1;
    int kb = t & 7; int h = t >> 3;
    int n = g * 16 + (lane & 15);
    int grow = (n >> 6) * HID + h * 64 + (n & 63);
    int col = kb * 64 + ks * 32 + (lane >> 4) * 8;
    cvt8_store(&dst[(size_t)i * 8], &src[(size_t)grow * HID + col]);
}

// ---------------- repack w_o -> fragment order ----------------
// chunk i = (((nt*8+kb)*2+ks)*8 + gg)*64 + lane; row = nt*128+gg*16+(lane&15).
// total chunks 4*8*2*8*64 = 32768 (= 512KB, exactly wob size).
__global__ void repack_wo_kernel(const float* __restrict__ src, short* __restrict__ dst) {
    int i = blockIdx.x * 256 + threadIdx.x;       // 32768 total
    int lane = i & 63, t = i >> 6;
    int gg = t & 7; t >>= 3;
    int ks = t & 1; t >>= 1;
    int kb = t & 7; int nt = t >> 3;
    int row = nt * 128 + gg * 16 + (lane & 15);
    int col = kb * 64 + ks * 32 + (lane >> 4) * 8;
    cvt8_store(&dst[(size_t)i * 8], &src[(size_t)row * HID + col]);
}

// ---------------- qkv + attention, one head per block ----------------
// grid 4096 = 512 m-tiles x 8 heads, 512 threads (8 waves).
// Tile M=128, N=192 (head h's Q|K|V cols), K=512, BK=64.
// A: LDS dbuf via gld16, XOR source-swizzle. B: registers, direct from
// repacked wqb (coalesced 1KB/load, L2-resident), 3-slot rotation prefetch.
__global__ __launch_bounds__(512, 4)
void qkv_head_kernel(const float* __restrict__ x, const short* __restrict__ xb, const int use_xb,
                     const float* __restrict__ wqf, const short* __restrict__ wqb, const int use_wb,
                     short* __restrict__ attnb, float* __restrict__ attnf, const int use_ab) {
    __shared__ __align__(16) union {
        struct { short a[2][128 * 64]; } st;                                       // 32768 B
        struct { short q[128 * 72]; short k[128 * 72]; short vt[64 * 152]; short p[8 * 16 * 40]; } at; // 66560 B
    } L;

    const int tid  = threadIdx.x;
    const int wave = tid >> 6;
    const int lane = tid & 63;
    const int ln   = lane & 15;
    const int q8   = (lane >> 4) * 8;
    const int qrow = (lane >> 4) * 4;
    const int wr   = wave >> 2;
    const int wc   = wave & 3;

    const int g   = blockIdx.x;
    const int xcd = g & 7;
    const int j   = g >> 3;
    const int h   = j & 7;
    const int mt  = (j >> 3) * 8 + xcd;
    const int m0  = mt * 128;

    float4v acc[4][3];
    #pragma unroll
    for (int fr = 0; fr < 4; ++fr)
        #pragma unroll
        for (int fc = 0; fc < 3; ++fc)
            acc[fr][fc] = (float4v){0.f, 0.f, 0.f, 0.f};

    // A staging: LDS dst linear chunk cg; global src column swizzled.
    auto stageA = [&](int buf, int kb) {
        if (use_xb) {
            #pragma unroll
            for (int i = 0; i < 2; ++i) {
                const int cg  = i * 512 + tid;
                const int row = cg >> 3;
                const int c8  = ((cg & 7) ^ (row & 7)) * 8;
                gld16(&xb[(size_t)(m0 + row) * HID + kb * 64 + c8],
                      &L.st.a[buf][(i * 512 + (wave << 6)) * 8]);
            }
        } else {
            #pragma unroll
            for (int i = 0; i < 2; ++i) {
                const int cg  = i * 512 + tid;
                const int row = cg >> 3;
                const int c8  = ((cg & 7) ^ (row & 7)) * 8;
                cvt8_store(&L.st.a[buf][cg * 8], &x[(size_t)(m0 + row) * HID + kb * 64 + c8]);
            }
        }
    };
    // B fragments for (kb, ks): 3 coalesced 16B/lane loads.
    auto loadKs = [&](short8* d, int kb, int ks) {
        if (use_wb) {
            #pragma unroll
            for (int fc = 0; fc < 3; ++fc) {
                const int chunk = ((h * 8 + kb) * 2 + ks) * 12 + wc * 3 + fc;
                d[fc] = *(const short8*)&wqb[(size_t)chunk * 512 + lane * 8];
            }
        } else {
            #pragma unroll
            for (int fc = 0; fc < 3; ++fc) {
                const int n    = (wc * 3 + fc) * 16 + ln;
                const int grow = (n >> 6) * HID + h * 64 + (n & 63);
                const float* s = &wqf[(size_t)grow * HID + kb * 64 + ks * 32 + q8];
                d[fc] = pack8(*(const float4v*)s, *(const float4v*)(s + 4));
            }
        }
    };

    short8 bf[3][3];
    loadKs(bf[0], 0, 0);
    loadKs(bf[1], 0, 1);
    stageA(0, 0);
    __syncthreads();               // drains vmcnt(0): tile 0 + frags resident

    #pragma unroll
    for (int kb = 0; kb < 8; ++kb) {
        const int cur = kb & 1;
        const int s0 = (2 * kb) % 3, s1 = (2 * kb + 1) % 3, sf = (2 * kb + 2) % 3;
        if (kb < 7) {
            stageA(cur ^ 1, kb + 1);
            loadKs(bf[sf], kb + 1, 0);
        }
        // ks = 0
        {
            const int cslot = (lane >> 4);
            short8 a[4];
            #pragma unroll
            for (int fr = 0; fr < 4; ++fr) {
                const int row = wr * 64 + fr * 16 + ln;
                a[fr] = *(const short8*)&L.st.a[cur][row * 64 + ((cslot ^ (row & 7)) << 3)];
            }
            #pragma unroll
            for (int fr = 0; fr < 4; ++fr)
                #pragma unroll
                for (int fc = 0; fc < 3; ++fc)
                    acc[fr][fc] = mfma16(a[fr], bf[s0][fc], acc[fr][fc]);
        }
        if (kb < 7) loadKs(bf[s0], kb + 1, 1);   // s0 now free; becomes next ks1
        // ks = 1
        {
            const int cslot = 4 + (lane >> 4);
            short8 a[4];
            #pragma unroll
            for (int fr = 0; fr < 4; ++fr) {
                const int row = wr * 64 + fr * 16 + ln;
                a[fr] = *(const short8*)&L.st.a[cur][row * 64 + ((cslot ^ (row & 7)) << 3)];
            }
            #pragma unroll
            for (int fr = 0; fr < 4; ++fr)
                #pragma unroll
                for (int fc = 0; fc < 3; ++fc)
                    acc[fr][fc] = mfma16(a[fr], bf[s1][fc], acc[fr][fc]);
        }
        __syncthreads();           // drains vmcnt + protects buf cur for reuse
    }
    // final barrier above retires staging; union region becomes Q/K/VT/P

    // epilogue: C frags -> Q (x0.125) / K / V^T bf16 in LDS
    #pragma unroll
    for (int fr = 0; fr < 4; ++fr) {
        #pragma unroll
        for (int fc = 0; fc < 3; ++fc) {
            const int nb = wc * 48 + fc * 16;        // wave-uniform region selector
            const int n  = nb + ln;
            const int mb = wr * 64 + fr * 16 + qrow;
            const float4v v = acc[fr][fc];
            if (nb < 64) {
                #pragma unroll
                for (int r = 0; r < 4; ++r)
                    L.at.q[(mb + r) * 72 + n] = bf16rne(v[r] * 0.125f);
            } else if (nb < 128) {
                #pragma unroll
                for (int r = 0; r < 4; ++r)
                    L.at.k[(mb + r) * 72 + (n - 64)] = bf16rne(v[r]);
            } else {
                #pragma unroll
                for (int r = 0; r < 4; ++r)
                    L.at.vt[(n - 128) * 152 + mb + r] = bf16rne(v[r]);
            }
        }
    }
    // zero VT tail cols [128,152) and P key-pad [16,32)
    for (int i = tid; i < 64 * 24; i += 512)
        L.at.vt[(i / 24) * 152 + 128 + (i % 24)] = 0;
    for (int i = tid; i < 8 * 16 * 16; i += 512)
        L.at.p[(i >> 8) * 640 + ((i >> 4) & 15) * 40 + 16 + (i & 15)] = 0;
    __syncthreads();

    // attention: wave w = batch w (tile rows 16w..16w+15)
    {
        const int rb = wave * 16;
        const short* qp = &L.at.q[(rb + ln) * 72 + q8];
        const short* kp = &L.at.k[(rb + ln) * 72 + q8];
        short8 aq0 = *(const short8*)qp;
        short8 aq1 = *(const short8*)(qp + 32);
        short8 bk0 = *(const short8*)kp;
        short8 bk1 = *(const short8*)(kp + 32);
        float4v s = (float4v){0.f, 0.f, 0.f, 0.f};
        s = mfma16(aq0, bk0, s);
        s = mfma16(aq1, bk1, s);     // s[r] = score[q=qrow+r][key=ln], pre-scaled

        float4v mx = s;
        #pragma unroll
        for (int off = 1; off < 16; off <<= 1)
            #pragma unroll
            for (int r = 0; r < 4; ++r)
                mx[r] = fmaxf(mx[r], __shfl_xor(mx[r], off));
        float4v p;
        #pragma unroll
        for (int r = 0; r < 4; ++r) p[r] = __expf(s[r] - mx[r]);
        float4v sm = p;
        #pragma unroll
        for (int off = 1; off < 16; off <<= 1)
            #pragma unroll
            for (int r = 0; r < 4; ++r)
                sm[r] += __shfl_xor(sm[r], off);
        #pragma unroll
        for (int r = 0; r < 4; ++r)
            L.at.p[wave * 640 + (qrow + r) * 40 + ln] = bf16rne(p[r] * __builtin_amdgcn_rcpf(sm[r]));

        short8 ap = *(const short8*)&L.at.p[wave * 640 + ln * 40 + q8];
        #pragma unroll
        for (int dc = 0; dc < 4; ++dc) {
            short8 bv = *(const short8*)&L.at.vt[(dc * 16 + ln) * 152 + rb + q8];
            float4v o = (float4v){0.f, 0.f, 0.f, 0.f};
            o = mfma16(ap, bv, o);
            #pragma unroll
            for (int r = 0; r < 4; ++r) {
                const size_t oi = (size_t)(m0 + rb + qrow + r) * HID + h * 64 + dc * 16 + ln;
                if (use_ab) attnb[oi] = bf16rne(o[r]);
                else        attnf[oi] = o[r];
            }
        }
    }
}

// ---------------- oproj: out = attn(bf16) @ w_o^T ----------------
// grid 2048 = 512 m-tiles x 4 n-tiles, 256 thr (4 waves, 2x2, 64x64/wave).
// A: LDS dbuf gld16 + swizzle. B: regs from repacked wob, 3-slot rotation.
// Only launched when use_ab==1 (tiers A/B; implies repacked wob).
__global__ __launch_bounds__(256, 3)
void oproj_kernel(const short* __restrict__ attnb, const short* __restrict__ wob,
                  float* __restrict__ out) {
    __shared__ __align__(16) short A[2][128 * 64];   // 32768 B total

    const int tid  = threadIdx.x;
    const int wave = tid >> 6;
    const int lane = tid & 63;
    const int ln   = lane & 15;
    const int qrow = (lane >> 4) * 4;
    const int wr   = wave >> 1;
    const int wc   = wave & 1;

    const int g   = blockIdx.x;
    const int xcd = g & 7;
    const int j   = g >> 3;
    const int nt  = j & 3;
    const int mt  = (j >> 2) * 8 + xcd;
    const int m0  = mt * 128;
    const int n0  = nt * 128;

    float4v acc[4][4];
    #pragma unroll
    for (int fr = 0; fr < 4; ++fr)
        #pragma unroll
        for (int fc = 0; fc < 4; ++fc)
            acc[fr][fc] = (float4v){0.f, 0.f, 0.f, 0.f};

    auto stageA = [&](int buf, int kb) {
        #pragma unroll
        for (int i = 0; i < 4; ++i) {
            const int cg  = i * 256 + tid;
            const int row = cg >> 3;
            const int c8  = ((cg & 7) ^ (row & 7)) * 8;
            gld16(&attnb[(size_t)(m0 + row) * HID + kb * 64 + c8],
                  &A[buf][(i * 256 + (wave << 6)) * 8]);
        }
    };
    auto loadKs = [&](short8* d, int kb, int ks) {
        #pragma unroll
        for (int fc = 0; fc < 4; ++fc) {
            const int chunk = ((nt * 8 + kb) * 2 + ks) * 8 + wc * 4 + fc;
            d[fc] = *(const short8*)&wob[(size_t)chunk * 512 + lane * 8];
        }
    };

    short8 bf[3][4];
    loadKs(bf[0], 0, 0);
    loadKs(bf[1], 0, 1);
    stageA(0, 0);
    __syncthreads();

    #pragma unroll
    for (int kb = 0; kb < 8; ++kb) {
        const int cur = kb & 1;
        const int s0 = (2 * kb) % 3, s1 = (2 * kb + 1) % 3, sf = (2 * kb + 2) % 3;
        if (kb < 7) {
            stageA(cur ^ 1, kb + 1);
            loadKs(bf[sf], kb + 1, 0);
        }
        {
            const int cslot = (lane >> 4);
            short8 a[4];
            #pragma unroll
            for (int fr = 0; fr < 4; ++fr) {
                const int row = wr * 64 + fr * 16 + ln;
                a[fr] = *(const short8*)&A[cur][row * 64 + ((cslot ^ (row & 7)) << 3)];
            }
            #pragma unroll
            for (int fr = 0; fr < 4; ++fr)
                #pragma unroll
                for (int fc = 0; fc < 4; ++fc)
                    acc[fr][fc] = mfma16(a[fr], bf[s0][fc], acc[fr][fc]);
        }
        if (kb < 7) loadKs(bf[s0], kb + 1, 1);
        {
            const int cslot = 4 + (lane >> 4);
            short8 a[4];
            #pragma unroll
            for (int fr = 0; fr < 4; ++fr) {
                const int row = wr * 64 + fr * 16 + ln;
                a[fr] = *(const short8*)&A[cur][row * 64 + ((cslot ^ (row & 7)) << 3)];
            }
            #pragma unroll
            for (int fr = 0; fr < 4; ++fr)
                #pragma unroll
                for (int fc = 0; fc < 4; ++fc)
                    acc[fr][fc] = mfma16(a[fr], bf[s1][fc], acc[fr][fc]);
        }
        __syncthreads();
    }

    #pragma unroll
    for (int fr = 0; fr < 4; ++fr)
        #pragma unroll
        for (int fc = 0; fc < 4; ++fc)
            #pragma unroll
            for (int r = 0; r < 4; ++r)
                out[(size_t)(m0 + wr * 64 + fr * 16 + qrow + r) * HID +
                    n0 + wc * 64 + fc * 16 + ln] = acc[fr][fc][r];
}

// ---------------- fallback oproj (tier C/D): in-place on d_out, R1-proven ----------------
// NOTE: expects OLD-linear wob layout (tier C converts wob linearly).
__global__ __launch_bounds__(512, 2)
void oproj_inplace_kernel(float* __restrict__ io, const float* __restrict__ wof,
                          const short* __restrict__ wob, const int use_wb) {
    __shared__ __align__(16) short sA[64 * 40];
    __shared__ __align__(16) short sW2[512 * 40];

    const int tid  = threadIdx.x;
    const int wave = tid >> 6;
    const int lane = tid & 63;
    const int ln   = lane & 15;
    const int q8   = (lane >> 4) * 8;
    const int qrow = (lane >> 4) * 4;
    const int m0   = blockIdx.x * 64;

    float4v acc[4][4];
    #pragma unroll
    for (int fr = 0; fr < 4; ++fr)
        #pragma unroll
        for (int fc = 0; fc < 4; ++fc)
            acc[fr][fc] = (float4v){0.f, 0.f, 0.f, 0.f};

    for (int kb = 0; kb < 16; ++kb) {
        __syncthreads();
        if (tid < 256) {
            int row = tid >> 2, c8 = (tid & 3) * 8;
            cvt8_store(&sA[row * 40 + c8], &io[(size_t)(m0 + row) * HID + kb * 32 + c8]);
        }
        #pragma unroll
        for (int it = 0; it < 4; ++it) {
            int gg = tid + it * 512;
            int n = gg >> 2, c8 = (gg & 3) * 8;
            if (use_wb)
                *(short8*)&sW2[n * 40 + c8] = *(const short8*)&wob[(size_t)n * HID + kb * 32 + c8];
            else
                cvt8_store(&sW2[n * 40 + c8], &wof[(size_t)n * HID + kb * 32 + c8]);
        }
        __syncthreads();
        short8 a[4], b[4];
        #pragma unroll
        for (int fr = 0; fr < 4; ++fr)
            a[fr] = *(const short8*)&sA[(fr * 16 + ln) * 40 + q8];
        #pragma unroll
        for (int fc = 0; fc < 4; ++fc)
            b[fc] = *(const short8*)&sW2[(wave * 64 + fc * 16 + ln) * 40 + q8];
        #pragma unroll
        for (int fr = 0; fr < 4; ++fr)
            #pragma unroll
            for (int fc = 0; fc < 4; ++fc)
                acc[fr][fc] = mfma16(a[fr], b[fc], acc[fr][fc]);
    }
    #pragma unroll
    for (int fr = 0; fr < 4; ++fr)
        #pragma unroll
        for (int fc = 0; fc < 4; ++fc)
            #pragma unroll
            for (int r = 0; r < 4; ++r)
                io[(size_t)(m0 + fr * 16 + qrow + r) * HID + wave * 64 + fc * 16 + ln] =
                    acc[fr][fc][r];
}

extern "C" void kernel_launch(void* const* d_in, const int* in_sizes, int n_in,
                              void* d_out, int out_size, void* d_ws, size_t ws_size,
                              hipStream_t stream) {
    const float* x    = (const float*)d_in[0];
    const float* wqkv = (const float*)d_in[1];
    const float* wo   = (const float*)d_in[2];
    float* out = (float*)d_out;

    const size_t n_x  = (size_t)65536 * HID;   // 33,554,432
    const size_t n_wq = (size_t)1536 * HID;    //    786,432
    const size_t n_wo = (size_t)HID * HID;     //    262,144
    const size_t szA = (n_x * 2 + n_wq + n_wo) * 2;   // xb + attnb + weights
    const size_t szB = (n_x + n_wq + n_wo) * 2;       // attnb + weights
    const size_t szC = (n_wq + n_wo) * 2;             // weights only

    short* xb = nullptr; short* attnb = nullptr; short* wqb = nullptr; short* wob = nullptr;
    int use_xb = 0, use_ab = 0, use_wb = 0;
    short* ws = (short*)d_ws;

    if (d_ws && ws_size >= szA) {
        use_xb = use_ab = use_wb = 1;
        xb = ws; attnb = xb + n_x; wqb = attnb + n_x; wob = wqb + n_wq;
    } else if (d_ws && ws_size >= szB) {
        use_ab = use_wb = 1;
        attnb = ws; wqb = attnb + n_x; wob = wqb + n_wq;
    } else if (d_ws && ws_size >= szC) {
        use_wb = 1;
        wqb = ws; wob = wqb + n_wq;
    }

    if (use_xb)
        cvt_kernel<<<(int)(n_x / 1024), 256, 0, stream>>>(x, xb, (int)(n_x / 4));
    if (use_wb) {
        repack_wq_kernel<<<384, 256, 0, stream>>>(wqkv, wqb);
        if (use_ab)
            repack_wo_kernel<<<128, 256, 0, stream>>>(wo, wob);   // fragment order
        else
            cvt_kernel<<<(int)(n_wo / 1024), 256, 0, stream>>>(wo, wob, (int)(n_wo / 4)); // linear for inplace
    }

    qkv_head_kernel<<<4096, 512, 0, stream>>>(x, xb, use_xb, wqkv, wqb, use_wb,
                                              attnb, out /*attnf*/, use_ab);

    if (use_ab)
        oproj_kernel<<<2048, 256, 0, stream>>>(attnb, wob, out);
    else
        oproj_inplace_kernel<<<1024, 512, 0, stream>>>(out, wo, wob, use_wb);
}

// Round 5
// 372.807 us; speedup vs baseline: 1.0968x; 1.0968x over previous
//
#include <hip/hip_runtime.h>

// GameURMAttention: x[65536,512] -> QKV -> 8-head SDPA (S=16,D=64) -> out-proj.
// R8 = R6 qkv (verbatim revert; R7's B-register qkv tripled HBM traffic and
// exposed mid-phase load latency at the barrier) + R7 oproj improved:
//  - oproj: A via gld16 dbuf+swizzle; B direct from fragment-repacked wob into
//    a 4-slot register rotation, BOTH ks frags of kb+1 issued at phase start
//    (nothing issued mid-phase -> nothing drained late at the barrier).
//  - prep_kernel fuses cvt_x + cvt_wq(linear) + repack_wo into one launch.
// Tiers:
//  tier A (ws>=137MB): xb + attnb + wqb(linear) + wob(fragment-packed)
//  tier B (ws>= 70MB): attnb + weights; x converted during qkv staging
//  tier C (ws>=  2MB): wqb linear + wob LINEAR (oproj_inplace needs it)
//  tier D:             all conversions on the fly

#define HID 512

typedef __attribute__((ext_vector_type(4))) float  float4v;
typedef __attribute__((ext_vector_type(8))) short  short8;
typedef __attribute__((ext_vector_type(4))) short  short4v;
typedef __attribute__((ext_vector_type(8))) __bf16 bf16x8;

static __device__ __forceinline__ short bf16rne(float f) {
    union { float f; unsigned u; } v; v.f = f;
    unsigned u = v.u + 0x7FFFu + ((v.u >> 16) & 1u);
    return (short)(u >> 16);
}

static __device__ __forceinline__ short8 pack8(float4v a, float4v b) {
    short8 o;
    o[0] = bf16rne(a[0]); o[1] = bf16rne(a[1]); o[2] = bf16rne(a[2]); o[3] = bf16rne(a[3]);
    o[4] = bf16rne(b[0]); o[5] = bf16rne(b[1]); o[6] = bf16rne(b[2]); o[7] = bf16rne(b[3]);
    return o;
}

static __device__ __forceinline__ void cvt8_store(short* dst, const float* src) {
    float4v a = *(const float4v*)src;
    float4v b = *(const float4v*)(src + 4);
    *(short8*)dst = pack8(a, b);
}

static __device__ __forceinline__ void cvt4_store(short* dst, const float* src) {
    float4v v = *(const float4v*)src;
    short4v o;
    o[0] = bf16rne(v[0]); o[1] = bf16rne(v[1]); o[2] = bf16rne(v[2]); o[3] = bf16rne(v[3]);
    *(short4v*)dst = o;
}

static __device__ __forceinline__ float4v mfma16(short8 a, short8 b, float4v c) {
    union { short8 s; bf16x8 v; } ua, ub;
    ua.s = a; ub.s = b;
    return __builtin_amdgcn_mfma_f32_16x16x32_bf16(ua.v, ub.v, c, 0, 0, 0);
}

// async global->LDS DMA, 16B per lane; l must be wave-uniform (HW adds lane*16).
static __device__ __forceinline__ void gld16(const short* g, short* l) {
    __builtin_amdgcn_global_load_lds(
        (const __attribute__((address_space(1))) void*)g,
        (__attribute__((address_space(3))) void*)l,
        16, 0, 0);
}

// ---------------- prep: x cvt + wq cvt (linear) + wo repack/cvt, one launch --------
// blocks [0,b_wq): x fp32->bf16 (short4 units). [b_wq,b_wo): wqkv linear cvt.
// [b_wo,grid): wo — fragment repack (wo_frag=1) or linear cvt (wo_frag=0).
// wo fragment chunk i = (((nt*8+kb)*2+ks)*8+gg)*64+lane;
//   row = nt*128+gg*16+(lane&15); col = kb*64+ks*32+(lane>>4)*8.
__global__ void prep_kernel(const float* __restrict__ x, short* __restrict__ xb,
                            const float* __restrict__ wqkv, short* __restrict__ wqb,
                            const float* __restrict__ wo, short* __restrict__ wob,
                            const int wo_frag, const int b_wq, const int b_wo) {
    const int blk = blockIdx.x, tid = threadIdx.x;
    if (blk < b_wq) {
        const size_t i = (size_t)blk * 256 + tid;              // n_x/4 units, exact
        cvt4_store(&xb[i * 4], &x[i * 4]);
    } else if (blk < b_wo) {
        const size_t i = (size_t)(blk - b_wq) * 256 + tid;     // n_wq/4 units, exact
        cvt4_store(&wqb[i * 4], &wqkv[i * 4]);
    } else if (wo_frag) {
        const int i = (blk - b_wo) * 256 + tid;                // 32768 chunks, exact
        const int lane = i & 63; int t = i >> 6;
        const int gg = t & 7; t >>= 3;
        const int ks = t & 1; t >>= 1;
        const int kb = t & 7; const int nt = t >> 3;
        const int row = nt * 128 + gg * 16 + (lane & 15);
        const int col = kb * 64 + ks * 32 + (lane >> 4) * 8;
        cvt8_store(&wob[(size_t)i * 8], &wo[(size_t)row * HID + col]);
    } else {
        const size_t i = (size_t)(blk - b_wo) * 256 + tid;     // n_wo/4 units, exact
        cvt4_store(&wob[i * 4], &wo[i * 4]);
    }
}

// ---------------- qkv + attention, one head per block (R6, proven) ----------------
// grid 4096 = 512 m-tiles x 8 heads, 512 threads (8 waves).
// Tile M=128, N=192 (head h's Q|K|V cols), K=512, BK=64, double-buffered.
// Waves: wr=wave>>2 (M half), wc=wave&3 (48-col strip). 12 MFMA / wave / ks.
// LDS tiles [rows][64] bf16, source-swizzled: slot s of row holds global
// 16B-chunk s^(row&7); reads use slot (ko>>3)^(row&7).
__global__ __launch_bounds__(512, 4)
void qkv_head_kernel(const float* __restrict__ x, const short* __restrict__ xb, const int use_xb,
                     const float* __restrict__ wqf, const short* __restrict__ wqb, const int use_wb,
                     short* __restrict__ attnb, float* __restrict__ attnf, const int use_ab) {
    __shared__ __align__(16) union {
        struct { short a[2][128 * 64]; short b[2][192 * 64]; } st;                 // 81920 B
        struct { short q[128 * 72]; short k[128 * 72]; short vt[64 * 152]; short p[8 * 16 * 40]; } at; // 66560 B
    } L;

    const int tid  = threadIdx.x;
    const int wave = tid >> 6;
    const int lane = tid & 63;
    const int ln   = lane & 15;
    const int q8   = (lane >> 4) * 8;
    const int qrow = (lane >> 4) * 4;
    const int wr   = wave >> 2;
    const int wc   = wave & 3;

    const int g   = blockIdx.x;
    const int xcd = g & 7;
    const int j   = g >> 3;
    const int h   = j & 7;
    const int mt  = (j >> 3) * 8 + xcd;
    const int m0  = mt * 128;

    float4v acc[4][3];
    #pragma unroll
    for (int fr = 0; fr < 4; ++fr)
        #pragma unroll
        for (int fc = 0; fc < 3; ++fc)
            acc[fr][fc] = (float4v){0.f, 0.f, 0.f, 0.f};

    // ---- staging helpers (buf/kb wave-uniform). LDS dst linear chunk cg;
    //      global src column swizzled: c8 = ((cg&7)^(row&7))*8.
    auto stageA = [&](int buf, int kb) {
        if (use_xb) {
            #pragma unroll
            for (int i = 0; i < 2; ++i) {
                const int cg  = i * 512 + tid;
                const int row = cg >> 3;
                const int c8  = ((cg & 7) ^ (row & 7)) * 8;
                gld16(&xb[(size_t)(m0 + row) * HID + kb * 64 + c8],
                      &L.st.a[buf][(i * 512 + (wave << 6)) * 8]);
            }
        } else {
            #pragma unroll
            for (int i = 0; i < 2; ++i) {
                const int cg  = i * 512 + tid;
                const int row = cg >> 3;
                const int c8  = ((cg & 7) ^ (row & 7)) * 8;
                cvt8_store(&L.st.a[buf][cg * 8], &x[(size_t)(m0 + row) * HID + kb * 64 + c8]);
            }
        }
    };
    auto stageB = [&](int buf, int kb) {
        if (use_wb) {
            #pragma unroll
            for (int i = 0; i < 3; ++i) {
                const int cg   = i * 512 + tid;
                const int n    = cg >> 3;
                const int c8   = ((cg & 7) ^ (n & 7)) * 8;
                const int grow = (n >> 6) * HID + h * 64 + (n & 63);
                gld16(&wqb[(size_t)grow * HID + kb * 64 + c8],
                      &L.st.b[buf][(i * 512 + (wave << 6)) * 8]);
            }
        } else {
            #pragma unroll
            for (int i = 0; i < 3; ++i) {
                const int cg   = i * 512 + tid;
                const int n    = cg >> 3;
                const int c8   = ((cg & 7) ^ (n & 7)) * 8;
                const int grow = (n >> 6) * HID + h * 64 + (n & 63);
                cvt8_store(&L.st.b[buf][cg * 8], &wqf[(size_t)grow * HID + kb * 64 + c8]);
            }
        }
    };

    // prologue: fill buffer 0 with kb=0
    stageA(0, 0);
    stageB(0, 0);
    __syncthreads();               // drains vmcnt(0): tile 0 resident

    int cur = 0;
    for (int kb = 0; kb < 8; ++kb) {
        if (kb < 7) {              // prefetch next tile into the other buffer
            stageA(cur ^ 1, kb + 1);
            stageB(cur ^ 1, kb + 1);
        }
        #pragma unroll
        for (int ks = 0; ks < 2; ++ks) {
            const int cslot = ks * 4 + (lane >> 4);   // 16B-chunk index of ko
            short8 a[4], b[3];
            #pragma unroll
            for (int fr = 0; fr < 4; ++fr) {
                const int row = wr * 64 + fr * 16 + ln;
                a[fr] = *(const short8*)&L.st.a[cur][row * 64 + ((cslot ^ (row & 7)) << 3)];
            }
            #pragma unroll
            for (int fc = 0; fc < 3; ++fc) {
                const int row = wc * 48 + fc * 16 + ln;
                b[fc] = *(const short8*)&L.st.b[cur][row * 64 + ((cslot ^ (row & 7)) << 3)];
            }
            #pragma unroll
            for (int fr = 0; fr < 4; ++fr)
                #pragma unroll
                for (int fc = 0; fc < 3; ++fc)
                    acc[fr][fc] = mfma16(a[fr], b[fc], acc[fr][fc]);
        }
        __syncthreads();           // drains residual vmcnt + protects buf cur for reuse
        cur ^= 1;
    }
    // final barrier above also retires staging; union region becomes Q/K/VT/P

    // epilogue: C frags -> Q (x0.125) / K / V^T bf16 in LDS
    #pragma unroll
    for (int fr = 0; fr < 4; ++fr) {
        #pragma unroll
        for (int fc = 0; fc < 3; ++fc) {
            const int nb = wc * 48 + fc * 16;        // wave-uniform region selector
            const int n  = nb + ln;
            const int mb = wr * 64 + fr * 16 + qrow;
            const float4v v = acc[fr][fc];
            if (nb < 64) {
                #pragma unroll
                for (int r = 0; r < 4; ++r)
                    L.at.q[(mb + r) * 72 + n] = bf16rne(v[r] * 0.125f);
            } else if (nb < 128) {
                #pragma unroll
                for (int r = 0; r < 4; ++r)
                    L.at.k[(mb + r) * 72 + (n - 64)] = bf16rne(v[r]);
            } else {
                #pragma unroll
                for (int r = 0; r < 4; ++r)
                    L.at.vt[(n - 128) * 152 + mb + r] = bf16rne(v[r]);
            }
        }
    }
    // zero VT tail cols [128,152) and P key-pad [16,32)
    for (int i = tid; i < 64 * 24; i += 512)
        L.at.vt[(i / 24) * 152 + 128 + (i % 24)] = 0;
    for (int i = tid; i < 8 * 16 * 16; i += 512)
        L.at.p[(i >> 8) * 640 + ((i >> 4) & 15) * 40 + 16 + (i & 15)] = 0;
    __syncthreads();

    // attention: wave w = batch w (tile rows 16w..16w+15)
    {
        const int rb = wave * 16;
        const short* qp = &L.at.q[(rb + ln) * 72 + q8];
        const short* kp = &L.at.k[(rb + ln) * 72 + q8];
        short8 aq0 = *(const short8*)qp;
        short8 aq1 = *(const short8*)(qp + 32);
        short8 bk0 = *(const short8*)kp;
        short8 bk1 = *(const short8*)(kp + 32);
        float4v s = (float4v){0.f, 0.f, 0.f, 0.f};
        s = mfma16(aq0, bk0, s);
        s = mfma16(aq1, bk1, s);     // s[r] = score[q=qrow+r][key=ln], pre-scaled

        float4v mx = s;
        #pragma unroll
        for (int off = 1; off < 16; off <<= 1)
            #pragma unroll
            for (int r = 0; r < 4; ++r)
                mx[r] = fmaxf(mx[r], __shfl_xor(mx[r], off));
        float4v p;
        #pragma unroll
        for (int r = 0; r < 4; ++r) p[r] = __expf(s[r] - mx[r]);
        float4v sm = p;
        #pragma unroll
        for (int off = 1; off < 16; off <<= 1)
            #pragma unroll
            for (int r = 0; r < 4; ++r)
                sm[r] += __shfl_xor(sm[r], off);
        #pragma unroll
        for (int r = 0; r < 4; ++r)
            L.at.p[wave * 640 + (qrow + r) * 40 + ln] = bf16rne(p[r] * __builtin_amdgcn_rcpf(sm[r]));

        short8 ap = *(const short8*)&L.at.p[wave * 640 + ln * 40 + q8];
        #pragma unroll
        for (int dc = 0; dc < 4; ++dc) {
            short8 bv = *(const short8*)&L.at.vt[(dc * 16 + ln) * 152 + rb + q8];
            float4v o = (float4v){0.f, 0.f, 0.f, 0.f};
            o = mfma16(ap, bv, o);
            #pragma unroll
            for (int r = 0; r < 4; ++r) {
                const size_t oi = (size_t)(m0 + rb + qrow + r) * HID + h * 64 + dc * 16 + ln;
                if (use_ab) attnb[oi] = bf16rne(o[r]);
                else        attnf[oi] = o[r];
            }
        }
    }
}

// ---------------- oproj: out = attn(bf16) @ w_o^T ----------------
// grid 2048 = 512 m-tiles x 4 n-tiles, 256 thr (4 waves, 2x2, 64x64/wave).
// A: LDS dbuf gld16 + swizzle. B: regs from fragment-repacked wob, 4-slot
// rotation, BOTH ks frags of kb+1 issued at phase start (nothing mid-phase).
// Only launched when use_ab==1 (tiers A/B; implies fragment-packed wob).
__global__ __launch_bounds__(256, 3)
void oproj_kernel(const short* __restrict__ attnb, const short* __restrict__ wob,
                  float* __restrict__ out) {
    __shared__ __align__(16) short A[2][128 * 64];   // 32768 B total

    const int tid  = threadIdx.x;
    const int wave = tid >> 6;
    const int lane = tid & 63;
    const int ln   = lane & 15;
    const int qrow = (lane >> 4) * 4;
    const int wr   = wave >> 1;
    const int wc   = wave & 1;

    const int g   = blockIdx.x;
    const int xcd = g & 7;
    const int j   = g >> 3;
    const int nt  = j & 3;
    const int mt  = (j >> 2) * 8 + xcd;
    const int m0  = mt * 128;
    const int n0  = nt * 128;

    float4v acc[4][4];
    #pragma unroll
    for (int fr = 0; fr < 4; ++fr)
        #pragma unroll
        for (int fc = 0; fc < 4; ++fc)
            acc[fr][fc] = (float4v){0.f, 0.f, 0.f, 0.f};

    auto stageA = [&](int buf, int kb) {
        #pragma unroll
        for (int i = 0; i < 4; ++i) {
            const int cg  = i * 256 + tid;
            const int row = cg >> 3;
            const int c8  = ((cg & 7) ^ (row & 7)) * 8;
            gld16(&attnb[(size_t)(m0 + row) * HID + kb * 64 + c8],
                  &A[buf][(i * 256 + (wave << 6)) * 8]);
        }
    };
    auto loadKs = [&](short8* d, int kb, int ks) {
        #pragma unroll
        for (int fc = 0; fc < 4; ++fc) {
            const int chunk = ((nt * 8 + kb) * 2 + ks) * 8 + wc * 4 + fc;
            d[fc] = *(const short8*)&wob[(size_t)chunk * 512 + lane * 8];
        }
    };

    short8 bf[4][4];
    loadKs(bf[0], 0, 0);
    loadKs(bf[1], 0, 1);
    stageA(0, 0);
    __syncthreads();

    #pragma unroll
    for (int kb = 0; kb < 8; ++kb) {
        const int cur = kb & 1;
        const int s0 = (2 * kb) & 3, s1 = (2 * kb + 1) & 3;
        const int t0 = (2 * kb + 2) & 3, t1 = (2 * kb + 3) & 3;
        if (kb < 7) {                    // ALL next-phase VMEM issued up front
            stageA(cur ^ 1, kb + 1);
            loadKs(bf[t0], kb + 1, 0);
            loadKs(bf[t1], kb + 1, 1);
        }
        {
            const int cslot = (lane >> 4);
            short8 a[4];
            #pragma unroll
            for (int fr = 0; fr < 4; ++fr) {
                const int row = wr * 64 + fr * 16 + ln;
                a[fr] = *(const short8*)&A[cur][row * 64 + ((cslot ^ (row & 7)) << 3)];
            }
            #pragma unroll
            for (int fr = 0; fr < 4; ++fr)
                #pragma unroll
                for (int fc = 0; fc < 4; ++fc)
                    acc[fr][fc] = mfma16(a[fr], bf[s0][fc], acc[fr][fc]);
        }
        {
            const int cslot = 4 + (lane >> 4);
            short8 a[4];
            #pragma unroll
            for (int fr = 0; fr < 4; ++fr) {
                const int row = wr * 64 + fr * 16 + ln;
                a[fr] = *(const short8*)&A[cur][row * 64 + ((cslot ^ (row & 7)) << 3)];
            }
            #pragma unroll
            for (int fr = 0; fr < 4; ++fr)
                #pragma unroll
                for (int fc = 0; fc < 4; ++fc)
                    acc[fr][fc] = mfma16(a[fr], bf[s1][fc], acc[fr][fc]);
        }
        __syncthreads();
    }

    #pragma unroll
    for (int fr = 0; fr < 4; ++fr)
        #pragma unroll
        for (int fc = 0; fc < 4; ++fc)
            #pragma unroll
            for (int r = 0; r < 4; ++r)
                out[(size_t)(m0 + wr * 64 + fr * 16 + qrow + r) * HID +
                    n0 + wc * 64 + fc * 16 + ln] = acc[fr][fc][r];
}

// ---------------- fallback oproj (tier C/D): in-place on d_out, R1-proven ----------------
// NOTE: expects LINEAR wob layout (tier C converts wob linearly).
__global__ __launch_bounds__(512, 2)
void oproj_inplace_kernel(float* __restrict__ io, const float* __restrict__ wof,
                          const short* __restrict__ wob, const int use_wb) {
    __shared__ __align__(16) short sA[64 * 40];
    __shared__ __align__(16) short sW2[512 * 40];

    const int tid  = threadIdx.x;
    const int wave = tid >> 6;
    const int lane = tid & 63;
    const int ln   = lane & 15;
    const int q8   = (lane >> 4) * 8;
    const int qrow = (lane >> 4) * 4;
    const int m0   = blockIdx.x * 64;

    float4v acc[4][4];
    #pragma unroll
    for (int fr = 0; fr < 4; ++fr)
        #pragma unroll
        for (int fc = 0; fc < 4; ++fc)
            acc[fr][fc] = (float4v){0.f, 0.f, 0.f, 0.f};

    for (int kb = 0; kb < 16; ++kb) {
        __syncthreads();
        if (tid < 256) {
            int row = tid >> 2, c8 = (tid & 3) * 8;
            cvt8_store(&sA[row * 40 + c8], &io[(size_t)(m0 + row) * HID + kb * 32 + c8]);
        }
        #pragma unroll
        for (int it = 0; it < 4; ++it) {
            int gg = tid + it * 512;
            int n = gg >> 2, c8 = (gg & 3) * 8;
            if (use_wb)
                *(short8*)&sW2[n * 40 + c8] = *(const short8*)&wob[(size_t)n * HID + kb * 32 + c8];
            else
                cvt8_store(&sW2[n * 40 + c8], &wof[(size_t)n * HID + kb * 32 + c8]);
        }
        __syncthreads();
        short8 a[4], b[4];
        #pragma unroll
        for (int fr = 0; fr < 4; ++fr)
            a[fr] = *(const short8*)&sA[(fr * 16 + ln) * 40 + q8];
        #pragma unroll
        for (int fc = 0; fc < 4; ++fc)
            b[fc] = *(const short8*)&sW2[(wave * 64 + fc * 16 + ln) * 40 + q8];
        #pragma unroll
        for (int fr = 0; fr < 4; ++fr)
            #pragma unroll
            for (int fc = 0; fc < 4; ++fc)
                acc[fr][fc] = mfma16(a[fr], b[fc], acc[fr][fc]);
    }
    #pragma unroll
    for (int fr = 0; fr < 4; ++fr)
        #pragma unroll
        for (int fc = 0; fc < 4; ++fc)
            #pragma unroll
            for (int r = 0; r < 4; ++r)
                io[(size_t)(m0 + fr * 16 + qrow + r) * HID + wave * 64 + fc * 16 + ln] =
                    acc[fr][fc][r];
}

extern "C" void kernel_launch(void* const* d_in, const int* in_sizes, int n_in,
                              void* d_out, int out_size, void* d_ws, size_t ws_size,
                              hipStream_t stream) {
    const float* x    = (const float*)d_in[0];
    const float* wqkv = (const float*)d_in[1];
    const float* wo   = (const float*)d_in[2];
    float* out = (float*)d_out;

    const size_t n_x  = (size_t)65536 * HID;   // 33,554,432
    const size_t n_wq = (size_t)1536 * HID;    //    786,432
    const size_t n_wo = (size_t)HID * HID;     //    262,144
    const size_t szA = (n_x * 2 + n_wq + n_wo) * 2;   // xb + attnb + weights
    const size_t szB = (n_x + n_wq + n_wo) * 2;       // attnb + weights
    const size_t szC = (n_wq + n_wo) * 2;             // weights only

    short* xb = nullptr; short* attnb = nullptr; short* wqb = nullptr; short* wob = nullptr;
    int use_xb = 0, use_ab = 0, use_wb = 0;
    short* ws = (short*)d_ws;

    if (d_ws && ws_size >= szA) {
        use_xb = use_ab = use_wb = 1;
        xb = ws; attnb = xb + n_x; wqb = attnb + n_x; wob = wqb + n_wq;
    } else if (d_ws && ws_size >= szB) {
        use_ab = use_wb = 1;
        attnb = ws; wqb = attnb + n_x; wob = wqb + n_wq;
    } else if (d_ws && ws_size >= szC) {
        use_wb = 1;
        wqb = ws; wob = wqb + n_wq;
    }

    if (use_wb) {
        // block counts: x = n_x/4/256 = 32768, wq = n_wq/4/256 = 768,
        // wo frag = (n_wo/8)/256 = 128, wo linear = n_wo/4/256 = 256
        const int nbx = use_xb ? 32768 : 0;
        const int b_wq = nbx;
        const int b_wo = nbx + 768;
        const int wo_frag = use_ab ? 1 : 0;
        const int grid = b_wo + (wo_frag ? 128 : 256);
        prep_kernel<<<grid, 256, 0, stream>>>(x, xb, wqkv, wqb, wo, wob,
                                              wo_frag, b_wq, b_wo);
    }

    qkv_head_kernel<<<4096, 512, 0, stream>>>(x, xb, use_xb, wqkv, wqb, use_wb,
                                              attnb, out /*attnf*/, use_ab);

    if (use_ab)
        oproj_kernel<<<2048, 256, 0, stream>>>(attnb, wob, out);
    else
        oproj_inplace_kernel<<<1024, 512, 0, stream>>>(out, wo, wob, use_wb);
}